// Round 1
// baseline (1845.800 us; speedup 1.0000x reference)
//
#include <hip/hip_runtime.h>
#include <hip/hip_bf16.h>

// GCN encoder: two graph-conv layers on N=50000 nodes, E=800000 edges.
// Layer1: agg1 = segsum(x[src]!=self, dst);  h = relu(agg1@W1r^T + x@W1s^T + b1)
// Layer2: t = h@W2r^T; agg2 = segsum(t[src], dst); out = agg2 + b2 + h@W2s^T
// (projection pushed before the scatter for layer 2 -- linearity of segment_sum)

#define N_NODES 50000
#define F_IN    96
#define HIDDEN  128
#define OUT_F   64

// ---------------- scatter: agg[dst] += feat[src] (skip self-loops) -----------
// one thread per (edge, 4-float chunk); consecutive threads cover consecutive
// chunks of the same source row -> coalesced float4 gather.
template<int F>
__global__ __launch_bounds__(256) void scatter_kernel(
    const float* __restrict__ feat, const int* __restrict__ ei,
    float* __restrict__ agg, int E)
{
    constexpr int F4 = F / 4;
    int gid = blockIdx.x * 256 + threadIdx.x;
    int e = gid / F4;
    int c = gid % F4;
    if (e >= E) return;
    int s = ei[e];
    int d = ei[E + e];
    if (s == d) return;                       // remove_self_loops
    float4 v = *(const float4*)&feat[(size_t)s * F + c * 4];
    float* p = &agg[(size_t)d * F + c * 4];
    unsafeAtomicAdd(p + 0, v.x);
    unsafeAtomicAdd(p + 1, v.y);
    unsafeAtomicAdd(p + 2, v.z);
    unsafeAtomicAdd(p + 3, v.w);
}

// ---------------- tiled fp32 GEMM:  C = act(A1@W1^T [+ A2@W2^T] + b [+ add]) -
// A: [N,K] row-major, W: [J,K] row-major, C: [N,J].
// LDS k-major tiles; 256 threads; each thread owns a 4x4 accumulator block.
template<int J, int K, int TILE_N, bool RELU, bool TWO, bool HAS_BIAS, bool HAS_ADDEND>
__global__ __launch_bounds__(256) void gemm_kernel(
    const float* __restrict__ A1, const float* __restrict__ A2,
    const float* __restrict__ W1, const float* __restrict__ W2,
    const float* __restrict__ bias, const float* __restrict__ addend,
    float* __restrict__ C, int N)
{
    constexpr int KC = 8;
    constexpr int ASTR = TILE_N + 4;          // pad keeps 16B align + kills write conflicts
    __shared__ float As[KC][ASTR];
    __shared__ float Ws[KC][J];

    const int tid = threadIdx.x;
    const int nblock = blockIdx.x * TILE_N;
    constexpr int NGRP = TILE_N / 4;          // 8 (TILE_N=32) or 16 (TILE_N=64)
    const int n0 = (tid % NGRP) * 4;
    const int j0 = (tid / NGRP) * 4;

    float acc[4][4] = {};

    constexpr int NCH = K / KC;
    constexpr int TOTCH = TWO ? 2 * NCH : NCH;

    for (int c = 0; c < TOTCH; ++c) {
        const bool second = TWO && (c >= NCH);
        const float* __restrict__ A = second ? A2 : A1;
        const float* __restrict__ W = second ? W2 : W1;
        const int kbase = (c % NCH) * KC;

        // --- stage A chunk (k-major / transposed) ---
        if (TILE_N == 32) {
            int n = tid / 8, k = tid % 8;
            int node = nblock + n;
            As[k][n] = (node < N) ? A[(size_t)node * K + kbase + k] : 0.f;
        } else {                               // TILE_N == 64
            int n = tid / 4, k = (tid % 4) * 2;
            int node = nblock + n;
            float2 v = make_float2(0.f, 0.f);
            if (node < N) v = *(const float2*)&A[(size_t)node * K + kbase + k];
            As[k][n] = v.x;
            As[k + 1][n] = v.y;
        }
        // --- stage W chunk (k-major) ---
        if (J == 128) {
            int j = tid / 2, koff = (tid % 2) * 4;
            float4 w = *(const float4*)&W[(size_t)j * K + kbase + koff];
            Ws[koff + 0][j] = w.x; Ws[koff + 1][j] = w.y;
            Ws[koff + 2][j] = w.z; Ws[koff + 3][j] = w.w;
        } else {                               // J == 64
            int j = tid / 4, koff = (tid % 4) * 2;
            float2 w = *(const float2*)&W[(size_t)j * K + kbase + koff];
            Ws[koff + 0][j] = w.x;
            Ws[koff + 1][j] = w.y;
        }
        __syncthreads();

        #pragma unroll
        for (int k = 0; k < KC; ++k) {
            float4 av = *(const float4*)&As[k][n0];
            float4 wv = *(const float4*)&Ws[k][j0];
            float a[4] = {av.x, av.y, av.z, av.w};
            float w[4] = {wv.x, wv.y, wv.z, wv.w};
            #pragma unroll
            for (int i = 0; i < 4; ++i)
                #pragma unroll
                for (int jj = 0; jj < 4; ++jj)
                    acc[i][jj] += a[i] * w[jj];
        }
        __syncthreads();
    }

    float bj[4] = {0.f, 0.f, 0.f, 0.f};
    if (HAS_BIAS) {
        bj[0] = bias[j0 + 0]; bj[1] = bias[j0 + 1];
        bj[2] = bias[j0 + 2]; bj[3] = bias[j0 + 3];
    }
    #pragma unroll
    for (int i = 0; i < 4; ++i) {
        int node = nblock + n0 + i;
        if (node >= N) continue;
        float4 o;
        o.x = acc[i][0] + bj[0];
        o.y = acc[i][1] + bj[1];
        o.z = acc[i][2] + bj[2];
        o.w = acc[i][3] + bj[3];
        if (HAS_ADDEND) {
            float4 ad = *(const float4*)&addend[(size_t)node * J + j0];
            o.x += ad.x; o.y += ad.y; o.z += ad.z; o.w += ad.w;
        }
        if (RELU) {
            o.x = fmaxf(o.x, 0.f); o.y = fmaxf(o.y, 0.f);
            o.z = fmaxf(o.z, 0.f); o.w = fmaxf(o.w, 0.f);
        }
        *(float4*)&C[(size_t)node * J + j0] = o;
    }
}

extern "C" void kernel_launch(void* const* d_in, const int* in_sizes, int n_in,
                              void* d_out, int out_size, void* d_ws, size_t ws_size,
                              hipStream_t stream) {
    const float* x       = (const float*)d_in[0];
    const int*   ei      = (const int*)d_in[1];
    const float* W1_rel  = (const float*)d_in[2];
    const float* b1      = (const float*)d_in[3];
    const float* W1_root = (const float*)d_in[4];
    const float* W2_rel  = (const float*)d_in[5];
    const float* b2      = (const float*)d_in[6];
    const float* W2_root = (const float*)d_in[7];
    float* out = (float*)d_out;

    const int N = in_sizes[0] / F_IN;       // 50000
    const int E = in_sizes[1] / 2;          // 800000

    char* ws = (char*)d_ws;
    float* agg1 = (float*)(ws);                                   // N*96  = 19.2 MB
    float* h    = (float*)(ws + (size_t)N * F_IN * 4);            // N*128 = 25.6 MB
    float* t    = (float*)(ws + (size_t)N * (F_IN + HIDDEN) * 4); // N*64  = 12.8 MB
    float* agg2 = (float*)(ws + (size_t)N * (F_IN + HIDDEN + OUT_F) * 4); // N*64

    hipMemsetAsync(agg1, 0, (size_t)N * F_IN * 4, stream);
    hipMemsetAsync(agg2, 0, (size_t)N * OUT_F * 4, stream);

    // layer 1 aggregation: agg1[dst] += x[src]
    {
        int total = E * (F_IN / 4);
        scatter_kernel<F_IN><<<(total + 255) / 256, 256, 0, stream>>>(x, ei, agg1, E);
    }
    // h = relu(agg1@W1_rel^T + x@W1_root^T + b1)
    gemm_kernel<HIDDEN, F_IN, 32, true, true, true, false>
        <<<(N + 31) / 32, 256, 0, stream>>>(agg1, x, W1_rel, W1_root, b1, nullptr, h, N);
    // t = h@W2_rel^T
    gemm_kernel<OUT_F, HIDDEN, 64, false, false, false, false>
        <<<(N + 63) / 64, 256, 0, stream>>>(h, nullptr, W2_rel, nullptr, nullptr, nullptr, t, N);
    // layer 2 aggregation: agg2[dst] += t[src]
    {
        int total = E * (OUT_F / 4);
        scatter_kernel<OUT_F><<<(total + 255) / 256, 256, 0, stream>>>(t, ei, agg2, E);
    }
    // out = agg2 + b2 + h@W2_root^T
    gemm_kernel<OUT_F, HIDDEN, 64, false, false, true, true>
        <<<(N + 63) / 64, 256, 0, stream>>>(h, nullptr, W2_root, nullptr, b2, agg2, out, N);
}

// Round 3
// 527.878 us; speedup vs baseline: 3.4966x; 3.4966x over previous
//
#include <hip/hip_runtime.h>
#include <hip/hip_bf16.h>

// GCN encoder: two graph-conv layers on N=50000 nodes, E=800000 edges.
// R3 = R2 (CSR + gather aggregation, no float atomics) with compacted
// workspace layout (~55 MB peak vs R2's 74 MB; R1's proven budget was 70.4 MB
// -- R2's container crash may have been ws overflow).
// Layer1: agg1 = segsum(x[src]!=self, dst);  h = relu(agg1@W1r^T + x@W1s^T + b1)
// Layer2: t = h@W2r^T; agg2 = segsum(t[src], dst); out = agg2 + b2 + h@W2s^T

#define N_NODES 50000
#define F_IN    96
#define HIDDEN  128
#define OUT_F   64

// ---------------- CSR build ------------------------------------------------
__global__ __launch_bounds__(256) void deg_kernel(
    const int* __restrict__ ei, int* __restrict__ deg, int E)
{
    int e = blockIdx.x * 256 + threadIdx.x;
    if (e >= E) return;
    int s = ei[e], d = ei[E + e];
    if (s != d) atomicAdd(&deg[d], 1);       // remove_self_loops
}

// single-block exclusive scan over deg[0..N) -> off[0..N], also copies to head
__global__ __launch_bounds__(256) void scan_kernel(
    const int* __restrict__ deg, int* __restrict__ off,
    int* __restrict__ head, int N)
{
    __shared__ int buf[256];
    __shared__ int carry;
    const int tid = threadIdx.x;
    if (tid == 0) carry = 0;
    __syncthreads();
    for (int base = 0; base < N; base += 256) {
        int i = base + tid;
        int v = (i < N) ? deg[i] : 0;
        buf[tid] = v;
        __syncthreads();
        #pragma unroll
        for (int s = 1; s < 256; s <<= 1) {
            int t = (tid >= s) ? buf[tid - s] : 0;
            __syncthreads();
            buf[tid] += t;
            __syncthreads();
        }
        int excl = buf[tid] - v;
        if (i < N) { int o = carry + excl; off[i] = o; head[i] = o; }
        __syncthreads();
        if (tid == 255) carry += buf[255];
        __syncthreads();
    }
    if (tid == 0) off[N] = carry;
}

__global__ __launch_bounds__(256) void place_kernel(
    const int* __restrict__ ei, int* __restrict__ head,
    int* __restrict__ csr_src, int E)
{
    int e = blockIdx.x * 256 + threadIdx.x;
    if (e >= E) return;
    int s = ei[e], d = ei[E + e];
    if (s == d) return;
    int p = atomicAdd(&head[d], 1);
    csr_src[p] = s;
}

// ---------------- gather aggregation: agg[n] = sum_{e: dst=n} feat[src_e] ----
// thread per (node, float4 chunk); src rows are L3-resident.
template<int F>
__global__ __launch_bounds__(256) void gather_agg(
    const float* __restrict__ feat, const int* __restrict__ off,
    const int* __restrict__ csr, float* __restrict__ agg, int N)
{
    constexpr int C = F / 4;
    int gid = blockIdx.x * 256 + threadIdx.x;
    int node = gid / C;
    int c = gid % C;
    if (node >= N) return;
    int j = off[node], end = off[node + 1];
    float4 acc = make_float4(0.f, 0.f, 0.f, 0.f);
    for (; j + 1 < end; j += 2) {              // 2x unroll for MLP
        int s0 = csr[j], s1 = csr[j + 1];
        float4 v0 = *(const float4*)&feat[(size_t)s0 * F + c * 4];
        float4 v1 = *(const float4*)&feat[(size_t)s1 * F + c * 4];
        acc.x += v0.x + v1.x; acc.y += v0.y + v1.y;
        acc.z += v0.z + v1.z; acc.w += v0.w + v1.w;
    }
    if (j < end) {
        int s0 = csr[j];
        float4 v0 = *(const float4*)&feat[(size_t)s0 * F + c * 4];
        acc.x += v0.x; acc.y += v0.y; acc.z += v0.z; acc.w += v0.w;
    }
    *(float4*)&agg[(size_t)node * F + c * 4] = acc;
}

// ---------------- tiled fp32 GEMM:  C = act(A1@W1^T [+ A2@W2^T] + b [+ add]) -
template<int J, int K, int TILE_N, bool RELU, bool TWO, bool HAS_BIAS, bool HAS_ADDEND>
__global__ __launch_bounds__(256) void gemm_kernel(
    const float* __restrict__ A1, const float* __restrict__ A2,
    const float* __restrict__ W1, const float* __restrict__ W2,
    const float* __restrict__ bias, const float* __restrict__ addend,
    float* __restrict__ C, int N)
{
    constexpr int KC = 8;
    constexpr int ASTR = TILE_N + 4;
    __shared__ float As[KC][ASTR];
    __shared__ float Ws[KC][J];

    const int tid = threadIdx.x;
    const int nblock = blockIdx.x * TILE_N;
    constexpr int NGRP = TILE_N / 4;
    const int n0 = (tid % NGRP) * 4;
    const int j0 = (tid / NGRP) * 4;

    float acc[4][4] = {};

    constexpr int NCH = K / KC;
    constexpr int TOTCH = TWO ? 2 * NCH : NCH;

    for (int c = 0; c < TOTCH; ++c) {
        const bool second = TWO && (c >= NCH);
        const float* __restrict__ A = second ? A2 : A1;
        const float* __restrict__ W = second ? W2 : W1;
        const int kbase = (c % NCH) * KC;

        if (TILE_N == 32) {
            int n = tid / 8, k = tid % 8;
            int node = nblock + n;
            As[k][n] = (node < N) ? A[(size_t)node * K + kbase + k] : 0.f;
        } else {
            int n = tid / 4, k = (tid % 4) * 2;
            int node = nblock + n;
            float2 v = make_float2(0.f, 0.f);
            if (node < N) v = *(const float2*)&A[(size_t)node * K + kbase + k];
            As[k][n] = v.x;
            As[k + 1][n] = v.y;
        }
        if (J == 128) {
            int j = tid / 2, koff = (tid % 2) * 4;
            float4 w = *(const float4*)&W[(size_t)j * K + kbase + koff];
            Ws[koff + 0][j] = w.x; Ws[koff + 1][j] = w.y;
            Ws[koff + 2][j] = w.z; Ws[koff + 3][j] = w.w;
        } else {
            int j = tid / 4, koff = (tid % 4) * 2;
            float2 w = *(const float2*)&W[(size_t)j * K + kbase + koff];
            Ws[koff + 0][j] = w.x;
            Ws[koff + 1][j] = w.y;
        }
        __syncthreads();

        #pragma unroll
        for (int k = 0; k < KC; ++k) {
            float4 av = *(const float4*)&As[k][n0];
            float4 wv = *(const float4*)&Ws[k][j0];
            float a[4] = {av.x, av.y, av.z, av.w};
            float w[4] = {wv.x, wv.y, wv.z, wv.w};
            #pragma unroll
            for (int i = 0; i < 4; ++i)
                #pragma unroll
                for (int jj = 0; jj < 4; ++jj)
                    acc[i][jj] += a[i] * w[jj];
        }
        __syncthreads();
    }

    float bj[4] = {0.f, 0.f, 0.f, 0.f};
    if (HAS_BIAS) {
        bj[0] = bias[j0 + 0]; bj[1] = bias[j0 + 1];
        bj[2] = bias[j0 + 2]; bj[3] = bias[j0 + 3];
    }
    #pragma unroll
    for (int i = 0; i < 4; ++i) {
        int node = nblock + n0 + i;
        if (node >= N) continue;
        float4 o;
        o.x = acc[i][0] + bj[0];
        o.y = acc[i][1] + bj[1];
        o.z = acc[i][2] + bj[2];
        o.w = acc[i][3] + bj[3];
        if (HAS_ADDEND) {
            float4 ad = *(const float4*)&addend[(size_t)node * J + j0];
            o.x += ad.x; o.y += ad.y; o.z += ad.z; o.w += ad.w;
        }
        if (RELU) {
            o.x = fmaxf(o.x, 0.f); o.y = fmaxf(o.y, 0.f);
            o.z = fmaxf(o.z, 0.f); o.w = fmaxf(o.w, 0.f);
        }
        *(float4*)&C[(size_t)node * J + j0] = o;
    }
}

extern "C" void kernel_launch(void* const* d_in, const int* in_sizes, int n_in,
                              void* d_out, int out_size, void* d_ws, size_t ws_size,
                              hipStream_t stream) {
    const float* x       = (const float*)d_in[0];
    const int*   ei      = (const int*)d_in[1];
    const float* W1_rel  = (const float*)d_in[2];
    const float* b1      = (const float*)d_in[3];
    const float* W1_root = (const float*)d_in[4];
    const float* W2_rel  = (const float*)d_in[5];
    const float* b2      = (const float*)d_in[6];
    const float* W2_root = (const float*)d_in[7];
    float* out = (float*)d_out;

    const int N = in_sizes[0] / F_IN;       // 50000
    const int E = in_sizes[1] / 2;          // 800000

    // Workspace layout with lifetime overlap (peak ~55 MB):
    //   [0, 25.6M)      h                  (live: gemm1 -> end)
    //   [25.6M, 44.8M)  agg1 (19.2M)       (live: gather1 -> gemm1)
    //   [25.6M, 38.4M)  t    (12.8M)       (live: gemm2a -> gather2; reuses agg1)
    //   [38.4M, 51.2M)  agg2 (12.8M)       (live: gather2 -> gemm3)
    //   [51.2M, ...)    deg/off/head/csr   (~3.8M)
    char* ws = (char*)d_ws;
    const size_t SZ_H    = (size_t)N_NODES * HIDDEN * 4;
    const size_t SZ_AGG1 = (size_t)N_NODES * F_IN * 4;
    const size_t SZ_T    = (size_t)N_NODES * OUT_F * 4;
    float* h    = (float*)(ws);
    float* agg1 = (float*)(ws + SZ_H);
    float* t    = (float*)(ws + SZ_H);                 // reuses agg1 region
    float* agg2 = (float*)(ws + SZ_H + SZ_T);          // 38.4M
    char* ip = ws + SZ_H + SZ_T + SZ_T;                // 51.2M
    int* deg  = (int*)(ip);            ip += (size_t)N_NODES * 4;
    int* off  = (int*)(ip);            ip += (size_t)(N_NODES + 1) * 4;
    int* head = (int*)(ip);            ip += (size_t)N_NODES * 4;
    int* csr  = (int*)(ip);
    (void)SZ_AGG1;

    // ---- CSR build (shared by both layers) ----
    hipMemsetAsync(deg, 0, (size_t)N * 4, stream);
    deg_kernel<<<(E + 255) / 256, 256, 0, stream>>>(ei, deg, E);
    scan_kernel<<<1, 256, 0, stream>>>(deg, off, head, N);
    place_kernel<<<(E + 255) / 256, 256, 0, stream>>>(ei, head, csr, E);

    // ---- layer 1 ----
    {
        int total = N * (F_IN / 4);
        gather_agg<F_IN><<<(total + 255) / 256, 256, 0, stream>>>(x, off, csr, agg1, N);
    }
    gemm_kernel<HIDDEN, F_IN, 32, true, true, true, false>
        <<<(N + 31) / 32, 256, 0, stream>>>(agg1, x, W1_rel, W1_root, b1, nullptr, h, N);

    // ---- layer 2 (projection pushed before the scatter) ----
    gemm_kernel<OUT_F, HIDDEN, 64, false, false, false, false>
        <<<(N + 63) / 64, 256, 0, stream>>>(h, nullptr, W2_rel, nullptr, nullptr, nullptr, t, N);
    {
        int total = N * (OUT_F / 4);
        gather_agg<OUT_F><<<(total + 255) / 256, 256, 0, stream>>>(t, off, csr, agg2, N);
    }
    gemm_kernel<OUT_F, HIDDEN, 64, false, false, true, true>
        <<<(N + 63) / 64, 256, 0, stream>>>(h, nullptr, W2_root, nullptr, b2, agg2, out, N);
}

// Round 5
// 329.004 us; speedup vs baseline: 5.6103x; 1.6045x over previous
//
#include <hip/hip_runtime.h>
#include <hip/hip_bf16.h>

// GCN encoder: two graph-conv layers on N=50000 nodes, E=800000 edges.
// R5 = R4 (order-free CSR alloc via wave-scan + atomic cursor, replacing the
// 214us single-block scan) with hard bounds guards on the CSR path so any
// latent corruption shows as wrong output, not a container crash.
// Layer1: agg1 = segsum(x[src]!=self, dst);  h = relu(agg1@W1r^T + x@W1s^T + b1)
// Layer2: t = h@W2r^T; agg2 = segsum(t[src], dst); out = agg2 + b2 + h@W2s^T

#define N_NODES 50000
#define F_IN    96
#define HIDDEN  128
#define OUT_F   64

// ---------------- CSR build ------------------------------------------------
__global__ __launch_bounds__(256) void deg_kernel(
    const int* __restrict__ ei, int* __restrict__ deg, int E)
{
    int e = blockIdx.x * 256 + threadIdx.x;
    if (e >= E) return;
    int s = ei[e], d = ei[E + e];
    if (s != d && (unsigned)d < (unsigned)N_NODES)
        atomicAdd(&deg[d], 1);               // remove_self_loops
}

// order-free segment allocation: off[n] = wave-base + lane-prefix(deg)
__global__ __launch_bounds__(256) void alloc_kernel(
    const int* __restrict__ deg, int* __restrict__ off,
    int* __restrict__ head, int* __restrict__ counter, int N)
{
    int i = blockIdx.x * 256 + threadIdx.x;
    int lane = threadIdx.x & 63;
    int v = (i < N) ? deg[i] : 0;
    int s = v;                                // inclusive scan over the wave
    #pragma unroll
    for (int d = 1; d < 64; d <<= 1) {
        int t = __shfl_up(s, d, 64);
        if (lane >= d) s += t;
    }
    int total = __shfl(s, 63, 64);
    int base = 0;
    if (lane == 63) base = atomicAdd(counter, total);
    base = __shfl(base, 63, 64);
    int o = base + s - v;                     // exclusive prefix
    if (i < N) { off[i] = o; head[i] = o; }
}

__global__ __launch_bounds__(256) void place_kernel(
    const int* __restrict__ ei, int* __restrict__ head,
    int* __restrict__ csr_src, int E)
{
    int e = blockIdx.x * 256 + threadIdx.x;
    if (e >= E) return;
    int s = ei[e], d = ei[E + e];
    if (s == d) return;
    if ((unsigned)d >= (unsigned)N_NODES) return;
    int p = atomicAdd(&head[d], 1);
    if ((unsigned)p < (unsigned)E)            // guard: invariant p < E
        csr_src[p] = s;
}

// ---------------- gather aggregation: agg[n] = sum_{e: dst=n} feat[src_e] ----
// thread per (node, float4 chunk); src rows are L3-resident.
// endp[] is head[] post-place (== off+deg).
template<int F>
__global__ __launch_bounds__(256) void gather_agg(
    const float* __restrict__ feat, const int* __restrict__ off,
    const int* __restrict__ endp, const int* __restrict__ csr,
    float* __restrict__ agg, int N, int E)
{
    constexpr int C = F / 4;
    int gid = blockIdx.x * 256 + threadIdx.x;
    int node = gid / C;
    int c = gid % C;
    if (node >= N) return;
    int j = off[node], end = endp[node];
    // guards: clamp to valid csr range (no-ops when invariants hold)
    if (j < 0) j = 0;
    if (end > E) end = E;
    float4 acc = make_float4(0.f, 0.f, 0.f, 0.f);
    for (; j + 1 < end; j += 2) {              // 2x unroll for MLP
        int s0 = csr[j], s1 = csr[j + 1];
        float4 v0 = *(const float4*)&feat[(size_t)s0 * F + c * 4];
        float4 v1 = *(const float4*)&feat[(size_t)s1 * F + c * 4];
        acc.x += v0.x + v1.x; acc.y += v0.y + v1.y;
        acc.z += v0.z + v1.z; acc.w += v0.w + v1.w;
    }
    if (j < end) {
        int s0 = csr[j];
        float4 v0 = *(const float4*)&feat[(size_t)s0 * F + c * 4];
        acc.x += v0.x; acc.y += v0.y; acc.z += v0.z; acc.w += v0.w;
    }
    *(float4*)&agg[(size_t)node * F + c * 4] = acc;
}

// ---------------- tiled fp32 GEMM:  C = act(A1@W1^T [+ A2@W2^T] + b [+ add]) -
template<int J, int K, int TILE_N, bool RELU, bool TWO, bool HAS_BIAS, bool HAS_ADDEND>
__global__ __launch_bounds__(256) void gemm_kernel(
    const float* __restrict__ A1, const float* __restrict__ A2,
    const float* __restrict__ W1, const float* __restrict__ W2,
    const float* __restrict__ bias, const float* __restrict__ addend,
    float* __restrict__ C, int N)
{
    constexpr int KC = 8;
    constexpr int ASTR = TILE_N + 4;
    __shared__ float As[KC][ASTR];
    __shared__ float Ws[KC][J];

    const int tid = threadIdx.x;
    const int nblock = blockIdx.x * TILE_N;
    constexpr int NGRP = TILE_N / 4;
    const int n0 = (tid % NGRP) * 4;
    const int j0 = (tid / NGRP) * 4;

    float acc[4][4] = {};

    constexpr int NCH = K / KC;
    constexpr int TOTCH = TWO ? 2 * NCH : NCH;

    for (int c = 0; c < TOTCH; ++c) {
        const bool second = TWO && (c >= NCH);
        const float* __restrict__ A = second ? A2 : A1;
        const float* __restrict__ W = second ? W2 : W1;
        const int kbase = (c % NCH) * KC;

        if (TILE_N == 32) {
            int n = tid / 8, k = tid % 8;
            int node = nblock + n;
            As[k][n] = (node < N) ? A[(size_t)node * K + kbase + k] : 0.f;
        } else {
            int n = tid / 4, k = (tid % 4) * 2;
            int node = nblock + n;
            float2 v = make_float2(0.f, 0.f);
            if (node < N) v = *(const float2*)&A[(size_t)node * K + kbase + k];
            As[k][n] = v.x;
            As[k + 1][n] = v.y;
        }
        if (J == 128) {
            int j = tid / 2, koff = (tid % 2) * 4;
            float4 w = *(const float4*)&W[(size_t)j * K + kbase + koff];
            Ws[koff + 0][j] = w.x; Ws[koff + 1][j] = w.y;
            Ws[koff + 2][j] = w.z; Ws[koff + 3][j] = w.w;
        } else {
            int j = tid / 4, koff = (tid % 4) * 2;
            float2 w = *(const float2*)&W[(size_t)j * K + kbase + koff];
            Ws[koff + 0][j] = w.x;
            Ws[koff + 1][j] = w.y;
        }
        __syncthreads();

        #pragma unroll
        for (int k = 0; k < KC; ++k) {
            float4 av = *(const float4*)&As[k][n0];
            float4 wv = *(const float4*)&Ws[k][j0];
            float a[4] = {av.x, av.y, av.z, av.w};
            float w[4] = {wv.x, wv.y, wv.z, wv.w};
            #pragma unroll
            for (int i = 0; i < 4; ++i)
                #pragma unroll
                for (int jj = 0; jj < 4; ++jj)
                    acc[i][jj] += a[i] * w[jj];
        }
        __syncthreads();
    }

    float bj[4] = {0.f, 0.f, 0.f, 0.f};
    if (HAS_BIAS) {
        bj[0] = bias[j0 + 0]; bj[1] = bias[j0 + 1];
        bj[2] = bias[j0 + 2]; bj[3] = bias[j0 + 3];
    }
    #pragma unroll
    for (int i = 0; i < 4; ++i) {
        int node = nblock + n0 + i;
        if (node >= N) continue;
        float4 o;
        o.x = acc[i][0] + bj[0];
        o.y = acc[i][1] + bj[1];
        o.z = acc[i][2] + bj[2];
        o.w = acc[i][3] + bj[3];
        if (HAS_ADDEND) {
            float4 ad = *(const float4*)&addend[(size_t)node * J + j0];
            o.x += ad.x; o.y += ad.y; o.z += ad.z; o.w += ad.w;
        }
        if (RELU) {
            o.x = fmaxf(o.x, 0.f); o.y = fmaxf(o.y, 0.f);
            o.z = fmaxf(o.z, 0.f); o.w = fmaxf(o.w, 0.f);
        }
        *(float4*)&C[(size_t)node * J + j0] = o;
    }
}

extern "C" void kernel_launch(void* const* d_in, const int* in_sizes, int n_in,
                              void* d_out, int out_size, void* d_ws, size_t ws_size,
                              hipStream_t stream) {
    const float* x       = (const float*)d_in[0];
    const int*   ei      = (const int*)d_in[1];
    const float* W1_rel  = (const float*)d_in[2];
    const float* b1      = (const float*)d_in[3];
    const float* W1_root = (const float*)d_in[4];
    const float* W2_rel  = (const float*)d_in[5];
    const float* b2      = (const float*)d_in[6];
    const float* W2_root = (const float*)d_in[7];
    float* out = (float*)d_out;

    const int N = in_sizes[0] / F_IN;       // 50000
    const int E = in_sizes[1] / 2;          // 800000

    // Workspace layout with lifetime overlap (peak ~55 MB):
    //   [0, 25.6M)      h                  (live: gemm1 -> end)
    //   [25.6M, 44.8M)  agg1 (19.2M)       (live: gather1 -> gemm1)
    //   [25.6M, 38.4M)  t    (12.8M)       (live: gemm2a -> gather2; reuses agg1)
    //   [38.4M, 51.2M)  agg2 (12.8M)       (live: gather2 -> gemm3)
    //   [51.2M, ...)    deg/counter/off/head/csr (~3.8M)
    char* ws = (char*)d_ws;
    const size_t SZ_H = (size_t)N_NODES * HIDDEN * 4;
    const size_t SZ_T = (size_t)N_NODES * OUT_F * 4;
    float* h    = (float*)(ws);
    float* agg1 = (float*)(ws + SZ_H);
    float* t    = (float*)(ws + SZ_H);                 // reuses agg1 region
    float* agg2 = (float*)(ws + SZ_H + SZ_T);
    char* ip = ws + SZ_H + SZ_T + SZ_T;
    int* deg     = (int*)(ip);         ip += (size_t)N_NODES * 4;
    int* counter = (int*)(ip);         ip += 4;
    int* off     = (int*)(ip);         ip += (size_t)N_NODES * 4;
    int* head    = (int*)(ip);         ip += (size_t)N_NODES * 4;
    int* csr     = (int*)(ip);

    // ---- CSR build (shared by both layers) ----
    hipMemsetAsync(deg, 0, (size_t)(N + 1) * 4, stream);   // deg + counter
    deg_kernel<<<(E + 255) / 256, 256, 0, stream>>>(ei, deg, E);
    alloc_kernel<<<(N + 255) / 256, 256, 0, stream>>>(deg, off, head, counter, N);
    place_kernel<<<(E + 255) / 256, 256, 0, stream>>>(ei, head, csr, E);

    // ---- layer 1 ----
    {
        int total = N * (F_IN / 4);
        gather_agg<F_IN><<<(total + 255) / 256, 256, 0, stream>>>(x, off, head, csr, agg1, N, E);
    }
    gemm_kernel<HIDDEN, F_IN, 32, true, true, true, false>
        <<<(N + 31) / 32, 256, 0, stream>>>(agg1, x, W1_rel, W1_root, b1, nullptr, h, N);

    // ---- layer 2 (projection pushed before the scatter) ----
    gemm_kernel<OUT_F, HIDDEN, 64, false, false, false, false>
        <<<(N + 63) / 64, 256, 0, stream>>>(h, nullptr, W2_rel, nullptr, nullptr, nullptr, t, N);
    {
        int total = N * (OUT_F / 4);
        gather_agg<OUT_F><<<(total + 255) / 256, 256, 0, stream>>>(t, off, head, csr, agg2, N, E);
    }
    gemm_kernel<OUT_F, HIDDEN, 64, false, false, true, true>
        <<<(N + 63) / 64, 256, 0, stream>>>(h, nullptr, W2_root, nullptr, b2, agg2, out, N);
}